// Round 7
// baseline (97.639 us; speedup 1.0000x reference)
//
#include <hip/hip_runtime.h>

#define ALPHA 0.2f

constexpr int N = 1024;
constexpr int F = 64;
constexpr int TI = 4;          // rows per block
constexpr int NB = N / TI;     // 256 blocks (1 per CU)
constexpr int NT = 1024;       // threads (== N: one j per thread in sweep A)
constexpr int NW = NT / 64;    // 16 waves

// Single fused GAT layer using  h' = elu( softmax(mask(leaky(e1+e2^T))) @ h @ W ),
// with e1 = h@(W@a1), e2 = h@(W@a2). No inter-block dependency -> one launch.
__global__ __launch_bounds__(NT, 4) void gat_one(const float* __restrict__ h,
                                                 const int* __restrict__ adj,
                                                 const float* __restrict__ W,
                                                 const float* __restrict__ a,
                                                 float* __restrict__ out) {
    const int i0 = blockIdx.x * TI;
    const int t = threadIdx.x;       // 0..1023
    const int wave = t >> 6;         // 0..15
    const int lane = t & 63;

    __shared__ float w1s[F], w2s[F];      // W@a1, W@a2
    __shared__ float e1s[TI];
    __shared__ float e2s[N];              // 4 KB
    __shared__ float p[TI][N];            // 16 KB exp-weights
    __shared__ float redsum[NW][TI];
    __shared__ float accs[NW][TI][F];     // 16 KB
    __shared__ float us[TI][F];           // normalized att@h

    // prefetch this thread's adj entries (independent of all phases below)
    int av[TI];
    #pragma unroll
    for (int r = 0; r < TI; ++r) av[r] = adj[(size_t)(i0 + r) * N + t];

    // ---- phase 0: w1 = W@a1, w2 = W@a2 (redundant per block, 8 KFLOP) ----
    {
        const int f = t >> 4;            // 0..63
        const int gq = t & 15;           // 0..15 -> 4 g's each
        const float4 wv  = *(const float4*)&W[f * F + gq * 4];
        const float4 a1v = *(const float4*)&a[gq * 4];
        const float4 a2v = *(const float4*)&a[F + gq * 4];
        float s1 = wv.x * a1v.x + wv.y * a1v.y + wv.z * a1v.z + wv.w * a1v.w;
        float s2 = wv.x * a2v.x + wv.y * a2v.y + wv.z * a2v.z + wv.w * a2v.w;
        #pragma unroll
        for (int off = 8; off > 0; off >>= 1) {
            s1 += __shfl_down(s1, off);
            s2 += __shfl_down(s2, off);
        }
        if (gq == 0) { w1s[f] = s1; w2s[f] = s2; }
    }
    __syncthreads();

    // ---- phase 1: e2[j] = h[j]·w2 for ALL j (wave per 64-row chunk);
    //      e1 for this block's own TI rows on the wave that covers them ----
    {
        const float w2v = w2s[lane];
        const float w1v = w1s[lane];
        const int jbase = wave * 64;
        #pragma unroll 2
        for (int s = 0; s < 64; ++s) {
            const int j = jbase + s;
            const float hv = h[(size_t)j * F + lane];   // coalesced 256 B/wave
            float v2 = hv * w2v;
            #pragma unroll
            for (int off = 32; off > 0; off >>= 1) v2 += __shfl_down(v2, off);
            if (lane == 0) e2s[j] = v2;
            if (j >= i0 && j < i0 + TI) {               // wave-uniform branch
                float v1 = hv * w1v;
                #pragma unroll
                for (int off = 32; off > 0; off >>= 1) v1 += __shfl_down(v1, off);
                if (lane == 0) e1s[j - i0] = v1;
            }
        }
    }
    __syncthreads();

    // ---- sweep A: p[r][t] = adj ? exp(leaky(e1+e2)) : 0  + row sums ----
    {
        const float ev = e2s[t];
        float lsum[TI];
        #pragma unroll
        for (int r = 0; r < TI; ++r) {
            float s = e1s[r] + ev;
            s = (s > 0.f) ? s : ALPHA * s;
            const float pe = (av[r] > 0) ? __expf(s) : 0.f;
            p[r][t] = pe;
            lsum[r] = pe;
        }
        #pragma unroll
        for (int off = 32; off > 0; off >>= 1) {
            #pragma unroll
            for (int r = 0; r < TI; ++r)
                lsum[r] += __shfl_down(lsum[r], off);
        }
        if (lane == 0) {
            #pragma unroll
            for (int r = 0; r < TI; ++r) redsum[wave][r] = lsum[r];
        }
    }
    __syncthreads();

    // ---- sweep B: u[r][f] = sum_j p[r][j] * h[j][f]; wave w covers 64 j ----
    {
        float a0 = 0.f, a1 = 0.f, a2 = 0.f, a3 = 0.f;
        const int j0 = wave * 64;
        #pragma unroll 4
        for (int j = j0; j < j0 + 64; j += 4) {
            const float4 p0 = *(const float4*)&p[0][j];
            const float4 p1 = *(const float4*)&p[1][j];
            const float4 p2 = *(const float4*)&p[2][j];
            const float4 p3 = *(const float4*)&p[3][j];
            #pragma unroll
            for (int u = 0; u < 4; ++u) {
                const float hv = h[(size_t)(j + u) * F + lane];  // L2-hot, coalesced
                a0 += (&p0.x)[u] * hv;
                a1 += (&p1.x)[u] * hv;
                a2 += (&p2.x)[u] * hv;
                a3 += (&p3.x)[u] * hv;
            }
        }
        accs[wave][0][lane] = a0;
        accs[wave][1][lane] = a1;
        accs[wave][2][lane] = a2;
        accs[wave][3][lane] = a3;
    }
    __syncthreads();

    // ---- epilogue A: reduce 16 waves, normalize -> us[r][f] ----
    if (t < TI * F) {
        const int r = t >> 6;
        const int f = t & 63;
        float s = 0.f, dn = 0.f;
        #pragma unroll
        for (int w = 0; w < NW; ++w) {
            s += accs[w][r][f];
            dn += redsum[w][r];
        }
        us[r][f] = s / dn;
    }
    __syncthreads();

    // ---- epilogue B: out[r][g] = elu( us[r][:] @ W[:][g] ) ----
    if (t < TI * F) {
        const int r = t >> 6;
        const int g = t & 63;
        float acc = 0.f;
        #pragma unroll
        for (int f = 0; f < F; ++f) {
            acc += us[r][f] * W[f * F + g];   // coalesced across g, L1-hot
        }
        out[(size_t)(i0 + r) * F + g] = (acc > 0.f) ? acc : expm1f(acc);
    }
}

extern "C" void kernel_launch(void* const* d_in, const int* in_sizes, int n_in,
                              void* d_out, int out_size, void* d_ws, size_t ws_size,
                              hipStream_t stream) {
    const float* h   = (const float*)d_in[0];
    const int*   adj = (const int*)d_in[1];
    const float* W   = (const float*)d_in[2];
    const float* a   = (const float*)d_in[3];
    float* out       = (float*)d_out;

    gat_one<<<NB, NT, 0, stream>>>(h, adj, W, a, out);
}

// Round 8
// 76.080 us; speedup vs baseline: 1.2834x; 1.2834x over previous
//
#include <hip/hip_runtime.h>

#define ALPHA 0.2f

constexpr int N = 1024;
constexpr int F = 64;
constexpr int TI = 4;          // rows per block
constexpr int NB = N / TI;     // 256 blocks
constexpr int NT = 1024;       // 16 waves
constexpr int NW = NT / 64;    // 16
constexpr int TJ = 256;        // tile rows (j) per pass
constexpr int NTILE = N / TJ;  // 4
constexpr int LDP = F + 1;     // 65: pad -> worst LDS aliasing is 2-way (free)

// One-launch fused GAT: h' = elu( (softmax(mask(leaky(e1+e2^T))) @ h) @ W ),
// e1 = h@(W@a1), e2 = h@(W@a2). e2 computed per-block from LDS-staged h tiles:
// the reduction rides on the coalesced tile load (4-deep, 16-lane) instead of
// round-7's serial 6-deep per-j shuffle chains.
__global__ __launch_bounds__(NT) void gat_tiled(const float* __restrict__ h,
                                                const int* __restrict__ adj,
                                                const float* __restrict__ W,
                                                const float* __restrict__ a,
                                                float* __restrict__ out) {
    const int i0 = blockIdx.x * TI;
    const int t = threadIdx.x;       // 0..1023
    const int wave = t >> 6;         // 0..15
    const int lane = t & 63;

    __shared__ float w1s[F], w2s[F];      // W@a1, W@a2
    __shared__ float e1s[TI];
    __shared__ float e2t[TJ];             // e2 for current tile
    __shared__ float tile[TJ * LDP];      // 66.6 KB h tile
    __shared__ float pt[TI][TJ];          // 4 KB exp-weights for current tile
    __shared__ float accs[NW][TI][F];     // 16 KB
    __shared__ float redsum[NW];          // wave w owns row w>>2, j-slice (w&3)
    __shared__ float us[TI][F];

    // ---- prefetch adj (coalesced; independent of everything below) ----
    const int pr = t >> 8;               // 0..3 row
    const int pj = t & 255;              // col within tile
    int av[NTILE];
    #pragma unroll
    for (int it = 0; it < NTILE; ++it)
        av[it] = adj[(size_t)(i0 + pr) * N + it * TJ + pj];

    // ---- phase 0: w1 = W@a1, w2 = W@a2 (8 KFLOP, redundant per block) ----
    {
        const int f = t >> 4;            // 0..63
        const int gq = t & 15;
        const float4 wv  = *(const float4*)&W[f * F + gq * 4];
        const float4 a1v = *(const float4*)&a[gq * 4];
        const float4 a2v = *(const float4*)&a[F + gq * 4];
        float s1 = wv.x*a1v.x + wv.y*a1v.y + wv.z*a1v.z + wv.w*a1v.w;
        float s2 = wv.x*a2v.x + wv.y*a2v.y + wv.z*a2v.z + wv.w*a2v.w;
        #pragma unroll
        for (int off = 8; off > 0; off >>= 1) {
            s1 += __shfl_down(s1, off);
            s2 += __shfl_down(s2, off);
        }
        if (gq == 0) { w1s[f] = s1; w2s[f] = s2; }
    }
    __syncthreads();

    // ---- e1 for this block's 4 rows (waves 0..3, one row each) ----
    if (wave < TI) {
        const float hv = h[(size_t)(i0 + wave) * F + lane];
        float v1 = hv * w1s[lane];
        #pragma unroll
        for (int off = 32; off > 0; off >>= 1) v1 += __shfl_down(v1, off);
        if (lane == 0) e1s[wave] = v1;
    }
    // visibility of e1s guaranteed by the barrier inside the first tile pass

    float u0 = 0.f, u1 = 0.f, u2 = 0.f, u3 = 0.f;   // att@h accumulators
    float rs = 0.f;                                  // rowsum (lane0 valid)
    const int rowq = wave * 4 + (lane >> 4);         // == t>>4
    const int colq = (lane & 15) * 4;

    for (int it = 0; it < NTILE; ++it) {
        const int j0 = it * TJ;

        // ---- tile load + e2 (reduction amortized over the float4 load) ----
        #pragma unroll
        for (int q = 0; q < 4; ++q) {
            const int row = q * 64 + rowq;
            const float4 hv4 = *(const float4*)&h[(size_t)(j0 + row) * F + colq];
            const float4 w2v = *(const float4*)&w2s[colq];
            float s2 = hv4.x*w2v.x + hv4.y*w2v.y + hv4.z*w2v.z + hv4.w*w2v.w;
            #pragma unroll
            for (int off = 8; off > 0; off >>= 1) s2 += __shfl_down(s2, off);
            if ((lane & 15) == 0) e2t[row] = s2;
            // pad-65: float4 store would be misaligned -> 4 scalar writes (2-way banks)
            tile[row * LDP + colq + 0] = hv4.x;
            tile[row * LDP + colq + 1] = hv4.y;
            tile[row * LDP + colq + 2] = hv4.z;
            tile[row * LDP + colq + 3] = hv4.w;
        }
        __syncthreads();

        // ---- sweep A: p = adj ? exp(leaky(e1+e2)) : 0, + row-slice sums ----
        {
            float s = e1s[pr] + e2t[pj];
            s = (s > 0.f) ? s : ALPHA * s;
            float pe = (av[it] > 0) ? __expf(s) : 0.f;
            pt[pr][pj] = pe;
            #pragma unroll
            for (int off = 32; off > 0; off >>= 1) pe += __shfl_down(pe, off);
            rs += pe;                    // lane0 accumulates this wave's slice
        }
        __syncthreads();

        // ---- sweep B: u[r][lane] += sum_{jj in wave's 16} p[r][jj]*tile[jj][lane] ----
        {
            const int jb = wave * 16;
            #pragma unroll
            for (int c = 0; c < 4; ++c) {
                const int jj = jb + c * 4;
                const float4 p0 = *(const float4*)&pt[0][jj];
                const float4 p1 = *(const float4*)&pt[1][jj];
                const float4 p2 = *(const float4*)&pt[2][jj];
                const float4 p3 = *(const float4*)&pt[3][jj];
                #pragma unroll
                for (int uu = 0; uu < 4; ++uu) {
                    const float tv = tile[(jj + uu) * LDP + lane];  // 2-way banks
                    u0 += (&p0.x)[uu] * tv;
                    u1 += (&p1.x)[uu] * tv;
                    u2 += (&p2.x)[uu] * tv;
                    u3 += (&p3.x)[uu] * tv;
                }
            }
        }
        __syncthreads();   // protect tile/pt/e2t before next pass
    }

    accs[wave][0][lane] = u0;
    accs[wave][1][lane] = u1;
    accs[wave][2][lane] = u2;
    accs[wave][3][lane] = u3;
    if (lane == 0) redsum[wave] = rs;
    __syncthreads();

    // ---- epilogue A: reduce 16 waves, normalize ----
    if (t < TI * F) {
        const int r = t >> 6;
        const int f = t & 63;
        float s = 0.f;
        #pragma unroll
        for (int w = 0; w < NW; ++w) s += accs[w][r][f];
        const float dn = redsum[4*r] + redsum[4*r+1] + redsum[4*r+2] + redsum[4*r+3];
        us[r][f] = s / dn;
    }
    __syncthreads();

    // ---- epilogue B: out[r][g] = elu( us[r][:] @ W[:][g] ) ----
    if (t < TI * F) {
        const int r = t >> 6;
        const int g = t & 63;
        float acc = 0.f;
        #pragma unroll
        for (int f = 0; f < F; ++f)
            acc += us[r][f] * W[f * F + g];   // coalesced across g, L1-hot
        out[(size_t)(i0 + r) * F + g] = (acc > 0.f) ? acc : expm1f(acc);
    }
}

extern "C" void kernel_launch(void* const* d_in, const int* in_sizes, int n_in,
                              void* d_out, int out_size, void* d_ws, size_t ws_size,
                              hipStream_t stream) {
    const float* h   = (const float*)d_in[0];
    const int*   adj = (const int*)d_in[1];
    const float* W   = (const float*)d_in[2];
    const float* a   = (const float*)d_in[3];
    float* out       = (float*)d_out;

    gat_tiled<<<NB, NT, 0, stream>>>(h, adj, W, a, out);
}

// Round 9
// 75.845 us; speedup vs baseline: 1.2874x; 1.0031x over previous
//
#include <hip/hip_runtime.h>

#define ALPHA 0.2f

constexpr int N = 1024;
constexpr int F = 64;
constexpr int TI = 4;          // rows per block
constexpr int NB = N / TI;     // 256 blocks
constexpr int NT = 1024;       // 16 waves
constexpr int NW = NT / 64;

// One-launch fused GAT: h' = elu( (softmax(mask(leaky(e1+e2^T))) @ h) @ W ),
// e1 = h@(W@a1), e2 = h@(W@a2).
// Memory structure == round-6 k2 (the best measured): sweep B reads h from L2,
// LDS ~38 KB -> 2 blocks/CU. e2 built in-kernel by the round-8 column-parallel
// pass (validated), WITHOUT the round-8 LDS tile staging (measured regression).
__global__ __launch_bounds__(NT) void gat_fused2(const float* __restrict__ h,
                                                 const int* __restrict__ adj,
                                                 const float* __restrict__ W,
                                                 const float* __restrict__ a,
                                                 float* __restrict__ out) {
    const int i0 = blockIdx.x * TI;
    const int t = threadIdx.x;       // 0..1023
    const int wave = t >> 6;         // 0..15
    const int lane = t & 63;

    __shared__ float w1s[F], w2s[F];      // W@a1, W@a2          0.5 KB
    __shared__ float e1s[TI];
    __shared__ float e2s[N];              // 4 KB
    __shared__ float p[TI][N];            // 16 KB exp-weights
    __shared__ float accs[NW][TI][F];     // 16 KB
    __shared__ float redsum[NW][TI];      // 256 B
    __shared__ float us[TI][F];           // 1 KB

    // ---- prefetch adj into registers (coalesced; independent of all phases) ----
    int av[TI];
    #pragma unroll
    for (int r = 0; r < TI; ++r) av[r] = adj[(size_t)(i0 + r) * N + t];

    // ---- phase 0: w1 = W@a1, w2 = W@a2 (8 KFLOP, redundant per block) ----
    {
        const int f = t >> 4;            // 0..63
        const int gq = t & 15;
        const float4 wv  = *(const float4*)&W[f * F + gq * 4];
        const float4 a1v = *(const float4*)&a[gq * 4];
        const float4 a2v = *(const float4*)&a[F + gq * 4];
        float s1 = wv.x*a1v.x + wv.y*a1v.y + wv.z*a1v.z + wv.w*a1v.w;
        float s2 = wv.x*a2v.x + wv.y*a2v.y + wv.z*a2v.z + wv.w*a2v.w;
        #pragma unroll
        for (int off = 8; off > 0; off >>= 1) {
            s1 += __shfl_down(s1, off);
            s2 += __shfl_down(s2, off);
        }
        if (gq == 0) { w1s[f] = s1; w2s[f] = s2; }
    }
    __syncthreads();

    // ---- e1 for this block's 4 rows (waves 0..3, one row each) ----
    if (wave < TI) {
        const float hv = h[(size_t)(i0 + wave) * F + lane];
        float v1 = hv * w1s[lane];
        #pragma unroll
        for (int off = 32; off > 0; off >>= 1) v1 += __shfl_down(v1, off);
        if (lane == 0) e1s[wave] = v1;
    }

    // ---- phase e2: e2[row] = h[row]·w2 for all rows; 16 independent passes.
    //      16 threads per row (float4 each), 4-deep shuffle reduce. ----
    {
        const int rq = t >> 4;           // 0..63
        const int cq = (t & 15) * 4;
        const float4 w2v = *(const float4*)&w2s[cq];
        #pragma unroll 4
        for (int pass = 0; pass < 16; ++pass) {
            const int row = pass * 64 + rq;
            const float4 hv4 = *(const float4*)&h[(size_t)row * F + cq];
            float s2 = hv4.x*w2v.x + hv4.y*w2v.y + hv4.z*w2v.z + hv4.w*w2v.w;
            #pragma unroll
            for (int off = 8; off > 0; off >>= 1) s2 += __shfl_down(s2, off);
            if ((t & 15) == 0) e2s[row] = s2;
        }
    }
    __syncthreads();

    // ---- sweep A: p[r][t] = adj ? exp(leaky(e1+e2)) : 0, + row sums ----
    {
        const float ev = e2s[t];
        float lsum[TI];
        #pragma unroll
        for (int r = 0; r < TI; ++r) {
            float s = e1s[r] + ev;
            s = (s > 0.f) ? s : ALPHA * s;
            const float pe = (av[r] > 0) ? __expf(s) : 0.f;
            p[r][t] = pe;
            lsum[r] = pe;
        }
        #pragma unroll
        for (int off = 32; off > 0; off >>= 1) {
            #pragma unroll
            for (int r = 0; r < TI; ++r)
                lsum[r] += __shfl_down(lsum[r], off);
        }
        if (lane == 0) {
            #pragma unroll
            for (int r = 0; r < TI; ++r) redsum[wave][r] = lsum[r];
        }
    }
    __syncthreads();

    // ---- sweep B: u[r][f] += sum_j p[r][j] * h[j][f]; wave w covers 64 j,
    //      lane = f; 4 rows share each coalesced L2-hot h load ----
    {
        float a0 = 0.f, a1 = 0.f, a2 = 0.f, a3 = 0.f;
        const int j0 = wave * 64;
        #pragma unroll 4
        for (int j = j0; j < j0 + 64; j += 4) {
            const float4 p0 = *(const float4*)&p[0][j];
            const float4 p1 = *(const float4*)&p[1][j];
            const float4 p2 = *(const float4*)&p[2][j];
            const float4 p3 = *(const float4*)&p[3][j];
            #pragma unroll
            for (int u = 0; u < 4; ++u) {
                const float hv = h[(size_t)(j + u) * F + lane];
                a0 += (&p0.x)[u] * hv;
                a1 += (&p1.x)[u] * hv;
                a2 += (&p2.x)[u] * hv;
                a3 += (&p3.x)[u] * hv;
            }
        }
        accs[wave][0][lane] = a0;
        accs[wave][1][lane] = a1;
        accs[wave][2][lane] = a2;
        accs[wave][3][lane] = a3;
    }
    __syncthreads();

    // ---- epilogue A: reduce 16 waves, normalize -> us ----
    if (t < TI * F) {
        const int r = t >> 6;
        const int f = t & 63;
        float s = 0.f, dn = 0.f;
        #pragma unroll
        for (int w = 0; w < NW; ++w) {
            s += accs[w][r][f];
            dn += redsum[w][r];
        }
        us[r][f] = s / dn;
    }
    __syncthreads();

    // ---- epilogue B: out[r][g] = elu( us[r][:] @ W[:][g] ) ----
    if (t < TI * F) {
        const int r = t >> 6;
        const int g = t & 63;
        float acc = 0.f;
        #pragma unroll
        for (int f = 0; f < F; ++f)
            acc += us[r][f] * W[f * F + g];   // coalesced across g, L1/L2-hot
        out[(size_t)(i0 + r) * F + g] = (acc > 0.f) ? acc : expm1f(acc);
    }
}

extern "C" void kernel_launch(void* const* d_in, const int* in_sizes, int n_in,
                              void* d_out, int out_size, void* d_ws, size_t ws_size,
                              hipStream_t stream) {
    const float* h   = (const float*)d_in[0];
    const int*   adj = (const int*)d_in[1];
    const float* W   = (const float*)d_in[2];
    const float* a   = (const float*)d_in[3];
    float* out       = (float*)d_out;

    gat_fused2<<<NB, NT, 0, stream>>>(h, adj, W, a, out);
}

// Round 10
// 69.569 us; speedup vs baseline: 1.4035x; 1.0902x over previous
//
#include <hip/hip_runtime.h>

#define ALPHA 0.2f

constexpr int N = 1024;
constexpr int F = 64;
constexpr int TI = 4;          // rows per block in k2
constexpr int NT = 1024;       // k2 threads, 16 waves
constexpr int NW = NT / 64;

// K1e: e1 = h@(W@a1), e2 = h@(W@a2). No Wh materialization (k2 uses (att@h)@W).
// grid: 256 blocks x 256 threads; each block: redundant tiny w1/w2, then 4 rows.
__global__ __launch_bounds__(256) void k1e(const float* __restrict__ h,
                                           const float* __restrict__ W,
                                           const float* __restrict__ a,
                                           float* __restrict__ e1,
                                           float* __restrict__ e2) {
    const int t = threadIdx.x;
    __shared__ float w1s[F], w2s[F];

    // w1 = W@a1, w2 = W@a2: thread t covers row f = t>>2, 16 cols
    {
        const int f = t >> 2;
        const int c0 = (t & 3) * 16;
        float s1 = 0.f, s2 = 0.f;
        #pragma unroll
        for (int q = 0; q < 4; ++q) {
            const float4 wv  = *(const float4*)&W[f * F + c0 + q * 4];
            const float4 a1v = *(const float4*)&a[c0 + q * 4];
            const float4 a2v = *(const float4*)&a[F + c0 + q * 4];
            s1 += wv.x*a1v.x + wv.y*a1v.y + wv.z*a1v.z + wv.w*a1v.w;
            s2 += wv.x*a2v.x + wv.y*a2v.y + wv.z*a2v.z + wv.w*a2v.w;
        }
        s1 += __shfl_down(s1, 2); s1 += __shfl_down(s1, 1);
        s2 += __shfl_down(s2, 2); s2 += __shfl_down(s2, 1);
        if ((t & 3) == 0) { w1s[f] = s1; w2s[f] = s2; }
    }
    __syncthreads();

    // wave w -> row i = blockIdx*4 + w; two dots of length 64
    const int wave = t >> 6;
    const int lane = t & 63;
    const int i = blockIdx.x * 4 + wave;
    const float hv = h[(size_t)i * F + lane];
    float v1 = hv * w1s[lane];
    float v2 = hv * w2s[lane];
    #pragma unroll
    for (int off = 32; off > 0; off >>= 1) {
        v1 += __shfl_down(v1, off);
        v2 += __shfl_down(v2, off);
    }
    if (lane == 0) {
        e1[i] = v1;
        e2[i] = v2;
    }
}

// K2e: TI rows/block, no-max softmax; u = att@h; out = elu(u@W).
__global__ __launch_bounds__(NT) void k2e(const int* __restrict__ adj,
                                          const float* __restrict__ h,
                                          const float* __restrict__ W,
                                          const float* __restrict__ e1,
                                          const float* __restrict__ e2,
                                          float* __restrict__ out) {
    const int i0 = blockIdx.x * TI;
    const int t = threadIdx.x;       // 0..1023
    const int wave = t >> 6;         // 0..15
    const int lane = t & 63;

    __shared__ float e2s[N];              // 4 KB
    __shared__ float e1s[TI];
    __shared__ float p[TI][N];            // 16 KB exp-weights
    __shared__ float accs[NW][TI][F];     // 16 KB
    __shared__ float redsum[NW];          // wave w owns row w>>2
    __shared__ float us[TI][F];           // 1 KB

    // ---- adj prefetch: one int4 per thread, issued before any wait ----
    const int r = t >> 8;                // 0..3 (wave-uniform: r = wave>>2)
    const int j4 = (t & 255) * 4;
    const int4 av = *(const int4*)&adj[(size_t)(i0 + r) * N + j4];

    e2s[t] = e2[t];
    if (t < TI) e1s[t] = e1[i0 + t];
    __syncthreads();

    // ---- sweep A: p[r][j] = adj ? exp(leaky(e1+e2)) : 0, + row sums ----
    {
        const float e1r = e1s[r];
        const float4 ev = *(const float4*)&e2s[j4];
        float4 pe;
        float s;
        s = e1r + ev.x; s = (s > 0.f) ? s : ALPHA * s; pe.x = (av.x > 0) ? __expf(s) : 0.f;
        s = e1r + ev.y; s = (s > 0.f) ? s : ALPHA * s; pe.y = (av.y > 0) ? __expf(s) : 0.f;
        s = e1r + ev.z; s = (s > 0.f) ? s : ALPHA * s; pe.z = (av.z > 0) ? __expf(s) : 0.f;
        s = e1r + ev.w; s = (s > 0.f) ? s : ALPHA * s; pe.w = (av.w > 0) ? __expf(s) : 0.f;
        *(float4*)&p[r][j4] = pe;
        float ls = (pe.x + pe.y) + (pe.z + pe.w);
        #pragma unroll
        for (int off = 32; off > 0; off >>= 1) ls += __shfl_down(ls, off);
        if (lane == 0) redsum[wave] = ls;     // partial for row wave>>2
    }
    __syncthreads();

    // ---- sweep B: u[r][f] += sum_j p[r][j]*h[j][f]; wave w covers 64 j ----
    {
        float a0 = 0.f, a1 = 0.f, a2 = 0.f, a3 = 0.f;
        const int j0 = wave * 64;
        #pragma unroll 4
        for (int j = j0; j < j0 + 64; j += 4) {
            const float4 p0 = *(const float4*)&p[0][j];   // wave-uniform: LDS broadcast
            const float4 p1 = *(const float4*)&p[1][j];
            const float4 p2 = *(const float4*)&p[2][j];
            const float4 p3 = *(const float4*)&p[3][j];
            #pragma unroll
            for (int u = 0; u < 4; ++u) {
                const float hv = h[(size_t)(j + u) * F + lane];  // coalesced, L2-hot
                a0 += (&p0.x)[u] * hv;
                a1 += (&p1.x)[u] * hv;
                a2 += (&p2.x)[u] * hv;
                a3 += (&p3.x)[u] * hv;
            }
        }
        accs[wave][0][lane] = a0;
        accs[wave][1][lane] = a1;
        accs[wave][2][lane] = a2;
        accs[wave][3][lane] = a3;
    }
    __syncthreads();

    // ---- epilogue A: reduce 16 waves, normalize -> us ----
    if (t < TI * F) {
        const int rr = t >> 6;
        const int f = t & 63;
        float su = 0.f;
        #pragma unroll
        for (int w = 0; w < NW; ++w) su += accs[w][rr][f];
        const float dn = redsum[4*rr] + redsum[4*rr+1] + redsum[4*rr+2] + redsum[4*rr+3];
        us[rr][f] = su / dn;
    }
    __syncthreads();

    // ---- epilogue B: out[r][g] = elu( us[r][:] @ W[:][g] ) ----
    if (t < TI * F) {
        const int rr = t >> 6;
        const int g = t & 63;
        float acc = 0.f;
        #pragma unroll
        for (int f = 0; f < F; ++f)
            acc += us[rr][f] * W[f * F + g];   // us: wave-uniform broadcast; W coalesced
        out[(size_t)(i0 + rr) * F + g] = (acc > 0.f) ? acc : expm1f(acc);
    }
}

extern "C" void kernel_launch(void* const* d_in, const int* in_sizes, int n_in,
                              void* d_out, int out_size, void* d_ws, size_t ws_size,
                              hipStream_t stream) {
    const float* h   = (const float*)d_in[0];
    const int*   adj = (const int*)d_in[1];
    const float* W   = (const float*)d_in[2];
    const float* a   = (const float*)d_in[3];
    float* out       = (float*)d_out;

    float* ws = (float*)d_ws;
    float* e1 = ws;        // N floats
    float* e2 = ws + N;    // N floats

    k1e<<<256, 256, 0, stream>>>(h, W, a, e1, e2);
    k2e<<<N / TI, NT, 0, stream>>>(adj, h, W, e1, e2, out);
}